// Round 6
// baseline (194.482 us; speedup 1.0000x reference)
//
#include <hip/hip_runtime.h>

// CTC batch loss (keras ctc_batch_cost), B=256, T=512, C=256, U=64.
// One 64-lane wave per batch, one block per CU. Lane l owns extended states
// 2l (blank) and 2l+1 (label l); lane 63 also owns state 128. Linear-domain
// forward recurrence with wave-uniform power-of-2 rescale every 8 steps.
//
// Data path: each time-row (256 floats = 1 KB) is staged with ONE coalesced
// global_load_lds dwordx4 (64 lanes x 16 B) into LDS, 4 buffers x 16-row
// chunks (64 KB), prefetch depth 3 (48 row-loads in flight, counted
// vmcnt(32) waits -- never drained to 0 in the main loop; 48 <= vmcnt cap 63).
//
// The per-step LDS gathers (row[label], row[255]) are issued as inline-asm
// ds_read_b32 so the compiler cannot see an LDS alias with the async
// global_load_lds writes and auto-insert a pipeline-draining
// s_waitcnt vmcnt(0) before them. Ordering is enforced manually:
//   - reads issue only after our counted vmcnt wait (volatile asm order),
//   - lgkmcnt(0) + sched_barrier(0) fence before any consumer (rule #18),
//   - write-after-read hazard covered because STAGE(c+3) targets buffer
//     (c-1)%4, whose reads drained at iteration c-1's lgkmcnt(0).

constexpr int B = 256, T = 512, C = 256, U = 64;
constexpr int CH = 16;   // time-steps per chunk
constexpr int NBUF = 4;  // LDS chunk buffers (64 KB total)
#define EPSF 1e-7f

__device__ __forceinline__ float dpp_wave_shr1(float x) {
    // alpha[2l-1]: previous lane's a_odd; lane 0 gets 0 (bound_ctrl).
    return __int_as_float(__builtin_amdgcn_update_dpp(
        0, __float_as_int(x), 0x138, 0xf, 0xf, true));
}

#define DPPMAX(ctrl)                                                      \
    {                                                                     \
        float x_ = __int_as_float(__builtin_amdgcn_update_dpp(            \
            0, __float_as_int(m_), (ctrl), 0xf, 0xf, true));              \
        m_ = fmaxf(m_, x_);                                               \
    }

#define RESCALE()                                                         \
    {                                                                     \
        float m_ = fmaxf(fmaxf(a_even, a_odd), a_top);                    \
        DPPMAX(0x111) DPPMAX(0x112) DPPMAX(0x114) DPPMAX(0x118)           \
        DPPMAX(0x142) DPPMAX(0x143)                                       \
        const float mx_ = __int_as_float(                                 \
            __builtin_amdgcn_readlane(__float_as_int(m_), 63));           \
        int e_ = (__float_as_int(mx_) >> 23) & 0xff;                      \
        int k_ = 187 - e_;                                                \
        k_ = k_ > 127 ? 127 : k_;                                         \
        const float s_ = __int_as_float((k_ + 127) << 23);                \
        a_even *= s_; a_odd *= s_; a_top *= s_;                           \
        esum += k_;                                                       \
    }

// Issue 16 coalesced row loads (1 KB each, one instruction per row) for
// chunk cc into rows[cc % NBUF]. Per-lane global source (row + lane*16B);
// wave-uniform LDS dest: HW writes lane l at dest + 16*l = linear row copy.
#define STAGE(cc)                                                          \
    {                                                                      \
        const int cs_ = (cc);                                              \
        float* lbase_ = &rows[cs_ % NBUF][0][0];                           \
        _Pragma("unroll")                                                  \
        for (int i = 0; i < CH; ++i) {                                     \
            int t = 1 + cs_ * CH + i;                                      \
            t = t < T ? t : T - 1;                                         \
            const float* g_ = rowp + (size_t)t * C + (lane << 2);          \
            __builtin_amdgcn_global_load_lds(                              \
                (const __attribute__((address_space(1))) void*)g_,         \
                (__attribute__((address_space(3))) void*)(lbase_ + i * C), \
                16, 0, 0);                                                 \
        }                                                                  \
    }

// Read chunk cc's per-step probabilities from LDS into registers via
// inline-asm ds_read (invisible to the compiler's alias analysis), then
// fence: lgkmcnt(0) + sched_barrier(0) before any consumer.
#define LDS_READ_ASM(cc)                                                   \
    {                                                                      \
        const int cr_ = (cc);                                              \
        float(*row_)[C] = rows[cr_ % NBUF];                                \
        const unsigned labA_ = (unsigned)(size_t)                          \
            (__attribute__((address_space(3))) void*)&row_[0][label];      \
        const unsigned blkA_ = (unsigned)(size_t)                          \
            (__attribute__((address_space(3))) void*)&row_[0][C - 1];      \
        _Pragma("unroll")                                                  \
        for (int i = 0; i < CH; ++i) {                                     \
            asm volatile("ds_read_b32 %0, %1"                              \
                         : "=v"(lab[i]) : "v"(labA_ + i * 1024));          \
            asm volatile("ds_read_b32 %0, %1"                              \
                         : "=v"(blk[i]) : "v"(blkA_ + i * 1024));          \
        }                                                                  \
        asm volatile("s_waitcnt lgkmcnt(0)" ::: "memory");                 \
        __builtin_amdgcn_sched_barrier(0);                                 \
    }

// NSTEPS recurrence steps. t = 1 + cc*CH + i; (t & 7) == 0 iff
// ((1 + i) & 7) == 0 (CH is a multiple of 8) -- compile-time cadence.
#define COMP_CHUNK(NSTEPS)                                                 \
    {                                                                      \
        _Pragma("unroll")                                                  \
        for (int i = 0; i < (NSTEPS); ++i) {                               \
            const float pb = blk[i] + EPSF;                                \
            const float pl = lab[i] + EPSF;                                \
            const float po = dpp_wave_shr1(a_odd);                         \
            const float skp = skip_ok ? po : 0.f;                          \
            const float ne = (a_even + po) * pb;                           \
            const float no = (a_odd + a_even + skp) * pl;                  \
            const float nt = (a_top + a_odd) * pb;                         \
            a_even = ne; a_odd = no; a_top = nt;                           \
            if (((1 + i) & 7) == 0) RESCALE();                             \
        }                                                                  \
    }

__global__ __launch_bounds__(64) void ctc_kernel(const int* __restrict__ y_true,
                                                 const float* __restrict__ y_pred,
                                                 float* __restrict__ out) {
    __shared__ float rows[NBUF][CH][C];  // 4 * 16 * 1KB = 64 KB
    const int b = blockIdx.x;
    const int lane = threadIdx.x;
    const int label = y_true[b * U + lane];
    const int label_prev = __shfl_up(label, 1);
    const bool skip_ok = (lane > 0) && (label != label_prev);
    const float* __restrict__ rowp = y_pred + (size_t)b * (T * C);

    // t = 0 init (linear domain; unreachable states = 0).
    float a_even, a_odd, a_top;
    {
        const float pb = rowp[C - 1] + EPSF;
        const float pl = rowp[label] + EPSF;
        a_even = (lane == 0) ? pb : 0.f;
        a_odd  = (lane == 0) ? pl : 0.f;
        a_top  = 0.f;
    }
    int esum = 0;  // stored = true * 2^esum

    // Prologue: fill the pipeline with chunks 0, 1, 2 (48 row-loads in flight).
    STAGE(0);
    STAGE(1);
    STAGE(2);

    float lab[CH], blk[CH];

    // Main loop, chunks 0..29. Steady state before the wait: chunks c, c+1,
    // c+2 outstanding (48); vmcnt(32) guarantees chunk c landed. STAGE(c+3)
    // then raises it back to 48 (max outstanding 48 <= 63 vmcnt cap).
    for (int c = 0; c < 30; ++c) {
        asm volatile("s_waitcnt vmcnt(32)" ::: "memory");
        __builtin_amdgcn_sched_barrier(0);
        if (c <= 28) STAGE(c + 3);
        LDS_READ_ASM(c);
        COMP_CHUNK(CH);
    }

    // Epilogue chunk 30: outstanding = chunks 30, 31 (32 loads).
    {
        asm volatile("s_waitcnt vmcnt(16)" ::: "memory");
        __builtin_amdgcn_sched_barrier(0);
        LDS_READ_ASM(30);
        COMP_CHUNK(CH);
    }
    // Epilogue chunk 31: t = 497..511 -> 15 steps.
    {
        asm volatile("s_waitcnt vmcnt(0)" ::: "memory");
        __builtin_amdgcn_sched_barrier(0);
        LDS_READ_ASM(31);
        COMP_CHUNK(CH - 1);
    }

    // loss = -ln(alpha[128] + alpha[127]); true = stored * 2^-esum
    if (lane == 63)
        out[b] = -logf(a_top + a_odd) + (float)esum * 0.69314718055994531f;
}

extern "C" void kernel_launch(void* const* d_in, const int* in_sizes, int n_in,
                              void* d_out, int out_size, void* d_ws, size_t ws_size,
                              hipStream_t stream) {
    const int* y_true   = (const int*)d_in[0];
    const float* y_pred = (const float*)d_in[1];
    float* out = (float*)d_out;
    hipLaunchKernelGGL(ctc_kernel, dim3(B), dim3(64), 0, stream,
                       y_true, y_pred, out);
}

// Round 7
// 193.323 us; speedup vs baseline: 1.0060x; 1.0060x over previous
//
#include <hip/hip_runtime.h>

// CTC batch loss (keras ctc_batch_cost), B=256, T=512, C=256, U=64.
// One 64-lane wave per batch, one block per CU. Lane l owns extended states
// 2l (blank) and 2l+1 (label l); lane 63 also owns state 128. Linear-domain
// forward recurrence with wave-uniform power-of-2 rescale every 8 steps.
//
// Timing model (r3/r6 evidence): dur_us = ~155us harness poison fills +
// kernel. Kernel ~38us, serial-execution-bound (1 wave/CU, no TLP; vmcnt
// slack of 3 chunks rules out memory service as the stall; fills prove
// ~6.9 TB/s deliverable). This round shaves the per-chunk serial path:
//   - all 32 ds_read_b32 use compile-time offset: immediates from one
//     per-chunk base (kills 32 address v_adds),
//   - STAGE issues moved after the ds_read issues so the 16 VMEM issues
//     overlap ds_read latency instead of preceding it.
// Ordering: counted vmcnt(32) waits (never 0 in main loop); ds_reads are
// alias-opaque inline asm; lgkmcnt(0) + sched_barrier(0) before consumers
// (rule #18). WAR: STAGE(c+3) targets buffer (c-1)%4 whose reads drained
// at iteration c-1's lgkmcnt(0).

constexpr int B = 256, T = 512, C = 256, U = 64;
constexpr int CH = 16;   // time-steps per chunk
constexpr int NBUF = 4;  // LDS chunk buffers (64 KB total)
#define EPSF 1e-7f

__device__ __forceinline__ float dpp_wave_shr1(float x) {
    // alpha[2l-1]: previous lane's a_odd; lane 0 gets 0 (bound_ctrl).
    return __int_as_float(__builtin_amdgcn_update_dpp(
        0, __float_as_int(x), 0x138, 0xf, 0xf, true));
}

#define DPPMAX(ctrl)                                                      \
    {                                                                     \
        float x_ = __int_as_float(__builtin_amdgcn_update_dpp(            \
            0, __float_as_int(m_), (ctrl), 0xf, 0xf, true));              \
        m_ = fmaxf(m_, x_);                                               \
    }

#define RESCALE()                                                         \
    {                                                                     \
        float m_ = fmaxf(fmaxf(a_even, a_odd), a_top);                    \
        DPPMAX(0x111) DPPMAX(0x112) DPPMAX(0x114) DPPMAX(0x118)           \
        DPPMAX(0x142) DPPMAX(0x143)                                       \
        const float mx_ = __int_as_float(                                 \
            __builtin_amdgcn_readlane(__float_as_int(m_), 63));           \
        int e_ = (__float_as_int(mx_) >> 23) & 0xff;                      \
        int k_ = 187 - e_;                                                \
        k_ = k_ > 127 ? 127 : k_;                                         \
        const float s_ = __int_as_float((k_ + 127) << 23);                \
        a_even *= s_; a_odd *= s_; a_top *= s_;                           \
        esum += k_;                                                       \
    }

// Issue 16 coalesced row loads (1 KB each, one instruction per row) for
// chunk cc into rows[cc % NBUF]. Per-lane global source (row + lane*16B);
// wave-uniform LDS dest: HW writes lane l at dest + 16*l = linear row copy.
#define STAGE(cc)                                                          \
    {                                                                      \
        const int cs_ = (cc);                                              \
        float* lbase_ = &rows[cs_ % NBUF][0][0];                           \
        _Pragma("unroll")                                                  \
        for (int i = 0; i < CH; ++i) {                                     \
            int t = 1 + cs_ * CH + i;                                      \
            t = t < T ? t : T - 1;                                         \
            const float* g_ = rowp + (size_t)t * C + (lane << 2);          \
            __builtin_amdgcn_global_load_lds(                              \
                (const __attribute__((address_space(1))) void*)g_,         \
                (__attribute__((address_space(3))) void*)(lbase_ + i * C), \
                16, 0, 0);                                                 \
        }                                                                  \
    }

// One ds_read_b32 with a compile-time literal byte offset (row stride 1KB).
#define DSR(dst, addr, OS)                                                 \
    asm volatile("ds_read_b32 %0, %1 offset:" OS                           \
                 : "=v"(dst) : "v"(addr));

// Issue chunk cc's 32 LDS gathers (labels per-lane, blanks broadcast).
// No fence here -- caller places lgkmcnt(0)+sched_barrier after STAGE.
#define LDS_ISSUE(cc)                                                      \
    {                                                                      \
        const int cr_ = (cc);                                              \
        float(*row_)[C] = rows[cr_ % NBUF];                                \
        const unsigned labA_ = (unsigned)(size_t)                          \
            (__attribute__((address_space(3))) void*)&row_[0][label];      \
        const unsigned blkA_ = (unsigned)(size_t)                          \
            (__attribute__((address_space(3))) void*)&row_[0][C - 1];      \
        DSR(lab[0],  labA_, "0")     DSR(lab[1],  labA_, "1024")           \
        DSR(lab[2],  labA_, "2048")  DSR(lab[3],  labA_, "3072")           \
        DSR(lab[4],  labA_, "4096")  DSR(lab[5],  labA_, "5120")           \
        DSR(lab[6],  labA_, "6144")  DSR(lab[7],  labA_, "7168")           \
        DSR(lab[8],  labA_, "8192")  DSR(lab[9],  labA_, "9216")           \
        DSR(lab[10], labA_, "10240") DSR(lab[11], labA_, "11264")          \
        DSR(lab[12], labA_, "12288") DSR(lab[13], labA_, "13312")          \
        DSR(lab[14], labA_, "14336") DSR(lab[15], labA_, "15360")          \
        DSR(blk[0],  blkA_, "0")     DSR(blk[1],  blkA_, "1024")           \
        DSR(blk[2],  blkA_, "2048")  DSR(blk[3],  blkA_, "3072")           \
        DSR(blk[4],  blkA_, "4096")  DSR(blk[5],  blkA_, "5120")           \
        DSR(blk[6],  blkA_, "6144")  DSR(blk[7],  blkA_, "7168")           \
        DSR(blk[8],  blkA_, "8192")  DSR(blk[9],  blkA_, "9216")           \
        DSR(blk[10], blkA_, "10240") DSR(blk[11], blkA_, "11264")          \
        DSR(blk[12], blkA_, "12288") DSR(blk[13], blkA_, "13312")          \
        DSR(blk[14], blkA_, "14336") DSR(blk[15], blkA_, "15360")          \
    }

#define LGKM_FENCE()                                                       \
    asm volatile("s_waitcnt lgkmcnt(0)" ::: "memory");                     \
    __builtin_amdgcn_sched_barrier(0);

// NSTEPS recurrence steps. t = 1 + cc*CH + i; (t & 7) == 0 iff
// ((1 + i) & 7) == 0 (CH is a multiple of 8) -- compile-time cadence.
#define COMP_CHUNK(NSTEPS)                                                 \
    {                                                                      \
        _Pragma("unroll")                                                  \
        for (int i = 0; i < (NSTEPS); ++i) {                               \
            const float pb = blk[i] + EPSF;                                \
            const float pl = lab[i] + EPSF;                                \
            const float po = dpp_wave_shr1(a_odd);                         \
            const float skp = skip_ok ? po : 0.f;                          \
            const float ne = (a_even + po) * pb;                           \
            const float no = (a_odd + a_even + skp) * pl;                  \
            const float nt = (a_top + a_odd) * pb;                         \
            a_even = ne; a_odd = no; a_top = nt;                           \
            if (((1 + i) & 7) == 0) RESCALE();                             \
        }                                                                  \
    }

__global__ __launch_bounds__(64) void ctc_kernel(const int* __restrict__ y_true,
                                                 const float* __restrict__ y_pred,
                                                 float* __restrict__ out) {
    __shared__ float rows[NBUF][CH][C];  // 4 * 16 * 1KB = 64 KB
    const int b = blockIdx.x;
    const int lane = threadIdx.x;
    const int label = y_true[b * U + lane];
    const int label_prev = __shfl_up(label, 1);
    const bool skip_ok = (lane > 0) && (label != label_prev);
    const float* __restrict__ rowp = y_pred + (size_t)b * (T * C);

    // t = 0 init (linear domain; unreachable states = 0).
    float a_even, a_odd, a_top;
    {
        const float pb = rowp[C - 1] + EPSF;
        const float pl = rowp[label] + EPSF;
        a_even = (lane == 0) ? pb : 0.f;
        a_odd  = (lane == 0) ? pl : 0.f;
        a_top  = 0.f;
    }
    int esum = 0;  // stored = true * 2^esum

    // Prologue: fill the pipeline with chunks 0, 1, 2 (48 row-loads in flight).
    STAGE(0);
    STAGE(1);
    STAGE(2);

    float lab[CH], blk[CH];

    // Main loop, chunks 0..29. Entering iteration c: chunks c, c+1, c+2
    // outstanding (48 loads); vmcnt(32) guarantees chunk c landed. ds_reads
    // issue first, then STAGE(c+3) overlaps their latency (outstanding back
    // to 48 <= 63 vmcnt cap), then one lgkm fence before compute.
    for (int c = 0; c < 30; ++c) {
        asm volatile("s_waitcnt vmcnt(32)" ::: "memory");
        __builtin_amdgcn_sched_barrier(0);
        LDS_ISSUE(c);
        __builtin_amdgcn_sched_barrier(0);
        if (c <= 28) STAGE(c + 3);
        LGKM_FENCE();
        COMP_CHUNK(CH);
    }

    // Epilogue chunk 30: outstanding = chunks 30, 31 (32 loads).
    {
        asm volatile("s_waitcnt vmcnt(16)" ::: "memory");
        __builtin_amdgcn_sched_barrier(0);
        LDS_ISSUE(30);
        LGKM_FENCE();
        COMP_CHUNK(CH);
    }
    // Epilogue chunk 31: t = 497..511 -> 15 steps.
    {
        asm volatile("s_waitcnt vmcnt(0)" ::: "memory");
        __builtin_amdgcn_sched_barrier(0);
        LDS_ISSUE(31);
        LGKM_FENCE();
        COMP_CHUNK(CH - 1);
    }

    // loss = -ln(alpha[128] + alpha[127]); true = stored * 2^-esum
    if (lane == 63)
        out[b] = -logf(a_top + a_odd) + (float)esum * 0.69314718055994531f;
}

extern "C" void kernel_launch(void* const* d_in, const int* in_sizes, int n_in,
                              void* d_out, int out_size, void* d_ws, size_t ws_size,
                              hipStream_t stream) {
    const int* y_true   = (const int*)d_in[0];
    const float* y_pred = (const float*)d_in[1];
    float* out = (float*)d_out;
    hipLaunchKernelGGL(ctc_kernel, dim3(B), dim3(64), 0, stream,
                       y_true, y_pred, out);
}